// Round 5
// baseline (1302.071 us; speedup 1.0000x reference)
//
#include <hip/hip_runtime.h>
#include <hip/hip_bf16.h>
#include <stdint.h>

#define BATCH 512
#define PIX   196
#define EDIM  2048
#define DDIM  512
#define ADIM  512
#define MROWS (BATCH*PIX)   // 100352 = 784*128

#define BM 128
#define BN 128
#define BK 32
#define NKT (EDIM/BK)       // 64

typedef __attribute__((ext_vector_type(8))) short bf16x8;
typedef __attribute__((ext_vector_type(8))) float f32x8;
typedef __attribute__((ext_vector_type(8))) __bf16 bf16v8;
typedef __attribute__((ext_vector_type(4))) float f32x4;

static __device__ __forceinline__ unsigned short f2bf(float f) {
  union { float f; uint32_t u; } v; v.f = f;
  uint32_t u = v.u;
  return (unsigned short)((u + 0x7FFFu + ((u >> 16) & 1u)) >> 16);  // RNE
}

// fp32x8 -> bf16x8 via compiler-selected v_cvt_pk_bf16_f32 (RNE)
static __device__ __forceinline__ bf16x8 cvt8(float4 a, float4 b) {
  f32x8 v = {a.x, a.y, a.z, a.w, b.x, b.y, b.z, b.w};
  bf16v8 c = __builtin_convertvector(v, bf16v8);
  bf16x8 r;
  __builtin_memcpy(&r, &c, 16);
  return r;
}

// ---------------- K0a: W_enc [2048][512] f32 -> Bt [512][2048] bf16 ----------
__global__ void k_transpose_wenc(const float* __restrict__ W,
                                 unsigned short* __restrict__ Bt) {
  __shared__ float tile[32][33];
  const int kt = blockIdx.x;            // 64 tiles over K
  const int nt = blockIdx.y;            // 16 tiles over N
  const int tx = threadIdx.x, ty = threadIdx.y;   // 32 x 8
#pragma unroll
  for (int j = 0; j < 4; j++)
    tile[ty + 8*j][tx] = W[(size_t)(kt*32 + ty + 8*j)*ADIM + nt*32 + tx];
  __syncthreads();
#pragma unroll
  for (int j = 0; j < 4; j++)
    Bt[(size_t)(nt*32 + ty + 8*j)*EDIM + kt*32 + tx] = f2bf(tile[tx][ty + 8*j]);
}

// ---------------- K0b: att2 = hidden @ W_dec + b_dec ------------------------
__global__ void k_att2(const float* __restrict__ H, const float* __restrict__ Wd,
                       const float* __restrict__ bd, float* __restrict__ att2) {
  __shared__ float h[DDIM];
  const int b = blockIdx.x;
  const int t = threadIdx.x;            // 256
  h[t]       = H[(size_t)b*DDIM + t];
  h[t + 256] = H[(size_t)b*DDIM + t + 256];
  __syncthreads();
  float a0 = 0.f, a1 = 0.f;
#pragma unroll 8
  for (int k = 0; k < DDIM; k++) {
    const float hv = h[k];
    a0 += hv * Wd[(size_t)k*ADIM + t];
    a1 += hv * Wd[(size_t)k*ADIM + t + 256];
  }
  att2[(size_t)b*ADIM + t]       = a0 + bd[t];
  att2[(size_t)b*ADIM + t + 256] = a1 + bd[t + 256];
}

// ---------------- K1: fused att1-GEMM + tanh + scores(partial) --------------
// grid 3136 (1D, XCD-swizzled, n-minor), 256 threads (4 waves, 2x2).
// NO LDS in the K-loop: each lane loads its MFMA fragments directly from
// global (A: fp32->cvt in reg, HBM/L2; B: bf16, L2-resident 2MB panel).
// Register pipeline: A prefetch depth-2 (3 sets live), B depth-1; unroll-4
// so every array index / pointer offset is compile-time.
__global__ __launch_bounds__(256, 2) void k_gemm_scores(
    const float* __restrict__ enc,          // [M][2048] f32
    const unsigned short* __restrict__ Bt,  // [512][2048] bf16
    const float* __restrict__ b_enc,        // [512]
    const float* __restrict__ att2,         // [B][512]
    const float* __restrict__ W_full,       // [512]
    float* __restrict__ scores)             // [M] (pre-zeroed, atomicAdd)
{
  __shared__ float sc[BM];

  const int t   = threadIdx.x;
  const int l   = t & 63;
  const int wid = t >> 6;
  const int wr  = wid >> 1, wc = wid & 1;

  // XCD swizzle (nwg=3136=8*392), n-minor: 4 N-tiles of one M-tile run
  // consecutively on the same XCD -> A rows fetched once, reused from L2.
  const int orig = blockIdx.x;
  const int tile = (orig & 7) * 392 + (orig >> 3);
  const int bm0 = (tile >> 2) * BM;
  const int bn0 = (tile & 3) * BN;

  if (t < BM) sc[t] = 0.f;

  const int l15 = l & 15, hi = l >> 4;

  // Per-lane fragment base pointers (k advances by 32 elems per tile).
  const float* pA[4];
  const unsigned short* pB[4];
#pragma unroll
  for (int mi = 0; mi < 4; mi++)
    pA[mi] = enc + (size_t)(bm0 + wr*64 + mi*16 + l15) * EDIM + hi*8;
#pragma unroll
  for (int ni = 0; ni < 4; ni++)
    pB[ni] = Bt + (size_t)(bn0 + wc*64 + ni*16 + l15) * EDIM + hi*8;

  float4 fa[4][4][2];   // [kt&3][mi][half] — at most 3 sets live
  bf16x8 fb[2][4];      // [kt&1][ni]
  f32x4 acc[4][4] = {};

  // prologue: A(0)->fa[0], A(1)->fa[1], B(0)->fb[0]
#pragma unroll
  for (int mi = 0; mi < 4; mi++) {
    fa[0][mi][0] = *(const float4*)(pA[mi]);
    fa[0][mi][1] = *(const float4*)(pA[mi] + 4);
    fa[1][mi][0] = *(const float4*)(pA[mi] + 32);
    fa[1][mi][1] = *(const float4*)(pA[mi] + 36);
  }
#pragma unroll
  for (int ni = 0; ni < 4; ni++)
    fb[0][ni] = *(const bf16x8*)(pB[ni]);

  for (int kb = 0; kb < NKT; kb += 4) {
#pragma unroll
    for (int p = 0; p < 4; p++) {
      const int kt = kb + p;
      if (kt + 2 < NKT) {     // prefetch A(kt+2), depth-2
#pragma unroll
        for (int mi = 0; mi < 4; mi++) {
          fa[(p+2)&3][mi][0] = *(const float4*)(pA[mi] + (p+2)*32);
          fa[(p+2)&3][mi][1] = *(const float4*)(pA[mi] + (p+2)*32 + 4);
        }
      }
      if (kt + 1 < NKT) {     // prefetch B(kt+1), depth-1
#pragma unroll
        for (int ni = 0; ni < 4; ni++)
          fb[(p+1)&1][ni] = *(const bf16x8*)(pB[ni] + (p+1)*32);
      }
      bf16x8 af[4];
#pragma unroll
      for (int mi = 0; mi < 4; mi++)
        af[mi] = cvt8(fa[p][mi][0], fa[p][mi][1]);
#pragma unroll
      for (int mi = 0; mi < 4; mi++)
#pragma unroll
        for (int ni = 0; ni < 4; ni++)
          acc[mi][ni] = __builtin_amdgcn_mfma_f32_16x16x32_bf16(
              af[mi], fb[p&1][ni], acc[mi][ni], 0, 0, 0);
    }
#pragma unroll
    for (int mi = 0; mi < 4; mi++) pA[mi] += 128;   // 4 tiles * 32 fp32
#pragma unroll
    for (int ni = 0; ni < 4; ni++) pB[ni] += 128;   // 4 tiles * 32 bf16
  }

  // epilogue: scores partial = sum_cols tanh(acc + b_enc + att2) * W_full
  const int lr = hi;           // 0..3
  const int lc = l15;
  float be[4], wf[4];
  int colv[4];
#pragma unroll
  for (int ni = 0; ni < 4; ni++) {
    colv[ni] = bn0 + wc*64 + ni*16 + lc;
    be[ni] = b_enc[colv[ni]];
    wf[ni] = W_full[colv[ni]];
  }
#pragma unroll
  for (int mi = 0; mi < 4; mi++) {
#pragma unroll
    for (int e = 0; e < 4; e++) {
      const int row_l = wr*64 + mi*16 + lr*4 + e;
      const unsigned gr = (unsigned)(bm0 + row_l);
      const unsigned b  = gr / 196u;
      float s = 0.f;
#pragma unroll
      for (int ni = 0; ni < 4; ni++) {
        const float v = acc[mi][ni][e] + be[ni] + att2[(size_t)b*ADIM + colv[ni]];
        s += tanhf(v) * wf[ni];
      }
      s += __shfl_xor(s, 1); s += __shfl_xor(s, 2);
      s += __shfl_xor(s, 4); s += __shfl_xor(s, 8);
      if (lc == 0) atomicAdd(&sc[row_l], s);
    }
  }
  __syncthreads();
  if (t < BM) atomicAdd(&scores[bm0 + t], sc[t]);
}

// ---------------- K2: softmax over P per batch (in place) -------------------
__global__ void k_softmax(float* __restrict__ sa) {   // [512][196]
  __shared__ float red[256];
  const int b = blockIdx.x, t = threadIdx.x;
  const float v = (t < PIX) ? sa[(size_t)b*PIX + t] : -1e30f;
  red[t] = v; __syncthreads();
  for (int s2 = 128; s2 > 0; s2 >>= 1) {
    if (t < s2) red[t] = fmaxf(red[t], red[t + s2]);
    __syncthreads();
  }
  const float m = red[0]; __syncthreads();
  const float e = (t < PIX) ? __expf(v - m) : 0.f;
  red[t] = e; __syncthreads();
  for (int s2 = 128; s2 > 0; s2 >>= 1) {
    if (t < s2) red[t] += red[t + s2];
    __syncthreads();
  }
  const float inv = 1.f / red[0];
  if (t < PIX) sa[(size_t)b*PIX + t] = e * inv;
}

// ---------------- K3: context = sum_p alpha[p] * enc[b][p][:] ---------------
__global__ __launch_bounds__(512) void k_context(
    const float* __restrict__ enc, const float* __restrict__ alpha,
    float* __restrict__ ctx) {
  __shared__ float al[PIX];
  const int b = blockIdx.x, t = threadIdx.x;
  if (t < PIX) al[t] = alpha[(size_t)b*PIX + t];
  __syncthreads();
  const float4* e4 = (const float4*)(enc + (size_t)b * PIX * EDIM);
  float4 acc = {0.f, 0.f, 0.f, 0.f};
#pragma unroll 4
  for (int p = 0; p < PIX; p++) {
    const float4 v = e4[(size_t)p * (EDIM/4) + t];
    const float a = al[p];
    acc.x += v.x * a; acc.y += v.y * a; acc.z += v.z * a; acc.w += v.w * a;
  }
  ((float4*)(ctx + (size_t)b * EDIM))[t] = acc;
}

// ---------------------------------------------------------------------------
extern "C" void kernel_launch(void* const* d_in, const int* in_sizes, int n_in,
                              void* d_out, int out_size, void* d_ws, size_t ws_size,
                              hipStream_t stream) {
  (void)in_sizes; (void)n_in; (void)out_size; (void)ws_size;
  const float* enc   = (const float*)d_in[0];
  const float* hid   = (const float*)d_in[1];
  const float* Wenc  = (const float*)d_in[2];
  const float* benc  = (const float*)d_in[3];
  const float* Wdec  = (const float*)d_in[4];
  const float* bdec  = (const float*)d_in[5];
  const float* Wfull = (const float*)d_in[6];
  // d_in[7] = b_full: softmax-invariant, unused.

  unsigned short* Bt = (unsigned short*)d_ws;                       // 2 MB
  float* att2 = (float*)((char*)d_ws + (size_t)ADIM * EDIM * 2);    // 1 MB
  float* ctx   = (float*)d_out;
  float* alpha = (float*)d_out + (size_t)BATCH * EDIM;              // scores live here

  hipMemsetAsync(alpha, 0, (size_t)MROWS * sizeof(float), stream);
  k_transpose_wenc<<<dim3(64, 16), dim3(32, 8), 0, stream>>>(Wenc, Bt);
  k_att2<<<BATCH, 256, 0, stream>>>(hid, Wdec, bdec, att2);
  k_gemm_scores<<<3136, 256, 0, stream>>>(enc, Bt, benc, att2, Wfull, alpha);
  k_softmax<<<BATCH, 256, 0, stream>>>(alpha);
  k_context<<<BATCH, 512, 0, stream>>>(enc, alpha, ctx);
}

// Round 6
// 703.725 us; speedup vs baseline: 1.8503x; 1.8503x over previous
//
#include <hip/hip_runtime.h>
#include <hip/hip_bf16.h>
#include <stdint.h>

#define BATCH 512
#define PIX   196
#define EDIM  2048
#define DDIM  512
#define ADIM  512
#define MROWS (BATCH*PIX)   // 100352 = 784*128

#define BM 128
#define BN 128
#define BK 32
#define NKT (EDIM/BK)       // 64

typedef __attribute__((ext_vector_type(8))) short bf16x8;
typedef __attribute__((ext_vector_type(8))) float f32x8;
typedef __attribute__((ext_vector_type(8))) __bf16 bf16v8;
typedef __attribute__((ext_vector_type(4))) float f32x4;

#define GLL16(g, lptr) __builtin_amdgcn_global_load_lds( \
    (const __attribute__((address_space(1))) void*)(g),  \
    (__attribute__((address_space(3))) void*)(lptr), 16, 0, 0)

static __device__ __forceinline__ unsigned short f2bf(float f) {
  union { float f; uint32_t u; } v; v.f = f;
  uint32_t u = v.u;
  return (unsigned short)((u + 0x7FFFu + ((u >> 16) & 1u)) >> 16);  // RNE
}

// fp32x8 -> bf16x8 via compiler-selected v_cvt_pk_bf16_f32 (RNE)
static __device__ __forceinline__ bf16x8 cvt8(float4 a, float4 b) {
  f32x8 v = {a.x, a.y, a.z, a.w, b.x, b.y, b.z, b.w};
  bf16v8 c = __builtin_convertvector(v, bf16v8);
  bf16x8 r;
  __builtin_memcpy(&r, &c, 16);
  return r;
}

// ---------------- K0a: W_enc [2048][512] f32 -> Bt [512][2048] bf16 ----------
__global__ void k_transpose_wenc(const float* __restrict__ W,
                                 unsigned short* __restrict__ Bt) {
  __shared__ float tile[32][33];
  const int kt = blockIdx.x;            // 64 tiles over K
  const int nt = blockIdx.y;            // 16 tiles over N
  const int tx = threadIdx.x, ty = threadIdx.y;   // 32 x 8
#pragma unroll
  for (int j = 0; j < 4; j++)
    tile[ty + 8*j][tx] = W[(size_t)(kt*32 + ty + 8*j)*ADIM + nt*32 + tx];
  __syncthreads();
#pragma unroll
  for (int j = 0; j < 4; j++)
    Bt[(size_t)(nt*32 + ty + 8*j)*EDIM + kt*32 + tx] = f2bf(tile[tx][ty + 8*j]);
}

// ---------------- K0b: att2 = hidden @ W_dec + b_dec ------------------------
__global__ void k_att2(const float* __restrict__ H, const float* __restrict__ Wd,
                       const float* __restrict__ bd, float* __restrict__ att2) {
  __shared__ float h[DDIM];
  const int b = blockIdx.x;
  const int t = threadIdx.x;            // 256
  h[t]       = H[(size_t)b*DDIM + t];
  h[t + 256] = H[(size_t)b*DDIM + t + 256];
  __syncthreads();
  float a0 = 0.f, a1 = 0.f;
#pragma unroll 8
  for (int k = 0; k < DDIM; k++) {
    const float hv = h[k];
    a0 += hv * Wd[(size_t)k*ADIM + t];
    a1 += hv * Wd[(size_t)k*ADIM + t + 256];
  }
  att2[(size_t)b*ADIM + t]       = a0 + bd[t];
  att2[(size_t)b*ADIM + t + 256] = a1 + bd[t + 256];
}

// ---------------- K1: fused att1-GEMM + tanh + scores(partial) --------------
// grid 3136 (1D, XCD-swizzled, n-minor), 256 threads (4 waves, 2x2).
// A: global fp32 -> regs -> cvt bf16 -> ds_write (T14 split, depth ~2 phases).
// B: bf16 via global_load_lds, depth-2.
// 3 LDS buffers (48.5 KB -> 3 blocks/CU); raw s_barrier + counted vmcnt(4):
// loads stay in flight across barriers (T3/T4). Unroll-6 => static indices.
__global__ __launch_bounds__(256, 3) void k_gemm_scores(
    const float* __restrict__ enc,          // [M][2048] f32
    const unsigned short* __restrict__ Bt,  // [512][2048] bf16
    const float* __restrict__ b_enc,        // [512]
    const float* __restrict__ att2,         // [B][512]
    const float* __restrict__ W_full,       // [512]
    float* __restrict__ scores)             // [M] (pre-zeroed, atomicAdd)
{
  __shared__ __align__(16) char ldsbuf[49152];   // 3x(8KB A + 8KB B)
  __shared__ float sc[BM];
  char* ldsA = ldsbuf;            // bufA[i] at i*8192
  char* ldsB = ldsbuf + 24576;    // bufB[i] at i*8192

  const int t   = threadIdx.x;
  const int l   = t & 63;
  const int wid = t >> 6;
  const int wr  = wid >> 1, wc = wid & 1;

  // XCD swizzle (nwg=3136=8*392), n-minor: 4 N-tiles of one M-tile run
  // consecutively on the same XCD -> A rows fetched once, reused from L2.
  const int orig = blockIdx.x;
  const int tile = (orig & 7) * 392 + (orig >> 3);
  const int bm0 = (tile >> 2) * BM;
  const int bn0 = (tile & 3) * BN;

  if (t < BM) sc[t] = 0.f;

  // ---- A staging maps (bf16 LDS tile [128 rows][32 cols], 16B chunks,
  //      chunk swizzle c' = c ^ ((row>>1)&3)) ----
  const int arow = t >> 1;
  const float* srcA = enc + (size_t)(bm0 + arow) * EDIM + (t & 1) * 16;
  const int aswz = (arow >> 1) & 3;
  const int wA0 = arow*64 + ((((t&1)*2 + 0) ^ aswz) * 16);
  const int wA1 = arow*64 + ((((t&1)*2 + 1) ^ aswz) * 16);

  // ---- B staging (linear dest; thread t -> byte t*16 + j*4096) ----
  const unsigned short* srcB0 = Bt + (size_t)(bn0 +      (t >> 2)) * EDIM + (t & 3) * 8;
  const unsigned short* srcB1 = Bt + (size_t)(bn0 + 64 + (t >> 2)) * EDIM + (t & 3) * 8;
  const int db0 = (0*4 + wid) * 1024;
  const int db1 = (1*4 + wid) * 1024;

  // ---- fragment read addresses (loop-invariant; buf/mi/ni are immediates) ----
  const int l15 = l & 15, hi = l >> 4;
  const int addrA = (wr*64 + l15)*64 + ((hi ^ ((l15 >> 1) & 3)) * 16);
  const int addrB = (wc*64 + l15)*64 + hi*16;

  float4 ar[2][4];      // two in-flight A k-tiles (16 fp32 each)
  f32x4 acc[4][4] = {};

#define A_ISSUE(SLOT, KT) do {                                  \
    const float* _s = srcA + (size_t)(KT)*BK;                   \
    ar[SLOT][0] = *(const float4*)(_s);                         \
    ar[SLOT][1] = *(const float4*)(_s + 4);                     \
    ar[SLOT][2] = *(const float4*)(_s + 8);                     \
    ar[SLOT][3] = *(const float4*)(_s + 12);                    \
  } while (0)

#define B_STAGE(NX2v, KT) do {                                  \
    GLL16(srcB0 + (size_t)(KT)*BK, ldsB + (NX2v)*8192 + db0);   \
    GLL16(srcB1 + (size_t)(KT)*BK, ldsB + (NX2v)*8192 + db1);   \
  } while (0)

#define A_WRITE(NX1v, CONS) do {                                \
    bf16x8 w0 = cvt8(ar[CONS][0], ar[CONS][1]);                 \
    bf16x8 w1 = cvt8(ar[CONS][2], ar[CONS][3]);                 \
    *(bf16x8*)(ldsA + (NX1v)*8192 + wA0) = w0;                  \
    *(bf16x8*)(ldsA + (NX1v)*8192 + wA1) = w1;                  \
  } while (0)

#define COMPUTE(CURv) do {                                      \
    bf16x8 af[4], bfr[4];                                       \
    _Pragma("unroll")                                           \
    for (int mi = 0; mi < 4; mi++)                              \
      af[mi] = *(const bf16x8*)(ldsA + (CURv)*8192 + mi*1024 + addrA); \
    _Pragma("unroll")                                           \
    for (int ni = 0; ni < 4; ni++)                              \
      bfr[ni] = *(const bf16x8*)(ldsB + (CURv)*8192 + ni*1024 + addrB); \
    _Pragma("unroll")                                           \
    for (int mi = 0; mi < 4; mi++)                              \
      _Pragma("unroll")                                         \
      for (int ni = 0; ni < 4; ni++)                            \
        acc[mi][ni] = __builtin_amdgcn_mfma_f32_16x16x32_bf16(  \
            af[mi], bfr[ni], acc[mi][ni], 0, 0, 0);             \
  } while (0)

  // steady-state iteration: at entry buf[CUR] ready; A(kt+1) regs + B(kt+1)
  // GLL in flight. vmcnt(4) keeps this iter's A(kt+2) loads flying.
#define ITER_FULL(KT, CURv, NX1v, NX2v, ISS, CONS) do {         \
    A_ISSUE(ISS, (KT)+2);                                       \
    COMPUTE(CURv);                                              \
    asm volatile("s_waitcnt vmcnt(4)" ::: "memory");            \
    A_WRITE(NX1v, CONS);                                        \
    B_STAGE(NX2v, (KT)+2);                                      \
    asm volatile("s_waitcnt lgkmcnt(0)" ::: "memory");          \
    __builtin_amdgcn_s_barrier();                               \
  } while (0)

  // ---- prologue ----
  A_ISSUE(0, 0);
  A_ISSUE(1, 1);
  B_STAGE(0, 0);
  B_STAGE(1, 1);
  asm volatile("s_waitcnt vmcnt(2)" ::: "memory");   // A(0),A(1),B(0) done
  A_WRITE(0, 0);
  asm volatile("s_waitcnt lgkmcnt(0)" ::: "memory");
  __builtin_amdgcn_s_barrier();

  // ---- main loop: kt = 0..59 (unroll 6 = lcm(2 reg slots, 3 bufs)) ----
  for (int kb = 0; kb < 60; kb += 6) {
    ITER_FULL(kb+0, 0,1,2, 0,1);
    ITER_FULL(kb+1, 1,2,0, 1,0);
    ITER_FULL(kb+2, 2,0,1, 0,1);
    ITER_FULL(kb+3, 0,1,2, 1,0);
    ITER_FULL(kb+4, 1,2,0, 0,1);
    ITER_FULL(kb+5, 2,0,1, 1,0);
  }
  // ---- tail: kt = 60..63 ----
  ITER_FULL(60, 0,1,2, 0,1);
  ITER_FULL(61, 1,2,0, 1,0);
  // kt=62: nothing new to issue; drain
  COMPUTE(2);
  asm volatile("s_waitcnt vmcnt(0)" ::: "memory");
  A_WRITE(0, 1);                       // A(63) -> bufA[0]
  asm volatile("s_waitcnt lgkmcnt(0)" ::: "memory");
  __builtin_amdgcn_s_barrier();
  // kt=63
  COMPUTE(0);

  // epilogue: scores partial = sum_cols tanh(acc + b_enc + att2) * W_full
  const int lr = hi;           // 0..3
  const int lc = l15;
  float be[4], wf[4];
  int colv[4];
#pragma unroll
  for (int ni = 0; ni < 4; ni++) {
    colv[ni] = bn0 + wc*64 + ni*16 + lc;
    be[ni] = b_enc[colv[ni]];
    wf[ni] = W_full[colv[ni]];
  }
#pragma unroll
  for (int mi = 0; mi < 4; mi++) {
#pragma unroll
    for (int e = 0; e < 4; e++) {
      const int row_l = wr*64 + mi*16 + lr*4 + e;
      const unsigned gr = (unsigned)(bm0 + row_l);
      const unsigned b  = gr / 196u;
      float s = 0.f;
#pragma unroll
      for (int ni = 0; ni < 4; ni++) {
        const float v = acc[mi][ni][e] + be[ni] + att2[(size_t)b*ADIM + colv[ni]];
        s += tanhf(v) * wf[ni];
      }
      s += __shfl_xor(s, 1); s += __shfl_xor(s, 2);
      s += __shfl_xor(s, 4); s += __shfl_xor(s, 8);
      if (lc == 0) atomicAdd(&sc[row_l], s);
    }
  }
  __syncthreads();
  if (t < BM) atomicAdd(&scores[bm0 + t], sc[t]);
}

// ---------------- K2: softmax over P per batch (in place) -------------------
__global__ void k_softmax(float* __restrict__ sa) {   // [512][196]
  __shared__ float red[256];
  const int b = blockIdx.x, t = threadIdx.x;
  const float v = (t < PIX) ? sa[(size_t)b*PIX + t] : -1e30f;
  red[t] = v; __syncthreads();
  for (int s2 = 128; s2 > 0; s2 >>= 1) {
    if (t < s2) red[t] = fmaxf(red[t], red[t + s2]);
    __syncthreads();
  }
  const float m = red[0]; __syncthreads();
  const float e = (t < PIX) ? __expf(v - m) : 0.f;
  red[t] = e; __syncthreads();
  for (int s2 = 128; s2 > 0; s2 >>= 1) {
    if (t < s2) red[t] += red[t + s2];
    __syncthreads();
  }
  const float inv = 1.f / red[0];
  if (t < PIX) sa[(size_t)b*PIX + t] = e * inv;
}

// ---------------- K3: context = sum_p alpha[p] * enc[b][p][:] ---------------
__global__ __launch_bounds__(512) void k_context(
    const float* __restrict__ enc, const float* __restrict__ alpha,
    float* __restrict__ ctx) {
  __shared__ float al[PIX];
  const int b = blockIdx.x, t = threadIdx.x;
  if (t < PIX) al[t] = alpha[(size_t)b*PIX + t];
  __syncthreads();
  const float4* e4 = (const float4*)(enc + (size_t)b * PIX * EDIM);
  float4 acc = {0.f, 0.f, 0.f, 0.f};
#pragma unroll 4
  for (int p = 0; p < PIX; p++) {
    const float4 v = e4[(size_t)p * (EDIM/4) + t];
    const float a = al[p];
    acc.x += v.x * a; acc.y += v.y * a; acc.z += v.z * a; acc.w += v.w * a;
  }
  ((float4*)(ctx + (size_t)b * EDIM))[t] = acc;
}

// ---------------------------------------------------------------------------
extern "C" void kernel_launch(void* const* d_in, const int* in_sizes, int n_in,
                              void* d_out, int out_size, void* d_ws, size_t ws_size,
                              hipStream_t stream) {
  (void)in_sizes; (void)n_in; (void)out_size; (void)ws_size;
  const float* enc   = (const float*)d_in[0];
  const float* hid   = (const float*)d_in[1];
  const float* Wenc  = (const float*)d_in[2];
  const float* benc  = (const float*)d_in[3];
  const float* Wdec  = (const float*)d_in[4];
  const float* bdec  = (const float*)d_in[5];
  const float* Wfull = (const float*)d_in[6];
  // d_in[7] = b_full: softmax-invariant, unused.

  unsigned short* Bt = (unsigned short*)d_ws;                       // 2 MB
  float* att2 = (float*)((char*)d_ws + (size_t)ADIM * EDIM * 2);    // 1 MB
  float* ctx   = (float*)d_out;
  float* alpha = (float*)d_out + (size_t)BATCH * EDIM;              // scores live here

  hipMemsetAsync(alpha, 0, (size_t)MROWS * sizeof(float), stream);
  k_transpose_wenc<<<dim3(64, 16), dim3(32, 8), 0, stream>>>(Wenc, Bt);
  k_att2<<<BATCH, 256, 0, stream>>>(hid, Wdec, bdec, att2);
  k_gemm_scores<<<3136, 256, 0, stream>>>(enc, Bt, benc, att2, Wfull, alpha);
  k_softmax<<<BATCH, 256, 0, stream>>>(alpha);
  k_context<<<BATCH, 512, 0, stream>>>(enc, alpha, ctx);
}